// Round 7
// baseline (373.067 us; speedup 1.0000x reference)
//
#include <hip/hip_runtime.h>
#include <hip/hip_bf16.h>

// RGCN 2-layer forward. dst-bucketed counting sort (rank = atomic return),
// per-(rel,dst) mean counts recovered via 32-bin LDS hist in l1/l2 prologue
// (NOT rel-grouped storage). l1/l2 pure gather, zero global accumulation
// atomics, zero per-edge LDS accumulation. 4-way edge ILP in count/scatter.
// Inputs are fp32 (verified: bf16 interpretation NaN'd in round 1); sniff
// flag retained as a safety net, fp32 path is the hot one.

constexpr int Nn = 50000;
constexpr int Hh = 16;
constexpr int Rr = 32;
constexpr int Cc = 8;
constexpr int Ee = 1600000;
constexpr int NBLK = (Nn + 255) / 256;   // 196
constexpr int CBLK = 1563;               // count/scatter blocks (4 edges/thread)
constexpr int CT   = CBLK * 256;         // 400128 threads; 4*CT >= Ee

__device__ __forceinline__ float b2f(__hip_bfloat16 v) { return __bfloat162float(v); }

// --- 0. dtype sniff (bf16 vs fp32 delivery) -----------------------------------
__global__ void sniff_kernel(const unsigned short* __restrict__ w, int* __restrict__ flag) {
    if (blockIdx.x == 0 && threadIdx.x == 0) {
        int hits = 0;
        for (int i = 0; i < 64; ++i) {
            unsigned short u = w[2 * i];
            int e = (u >> 7) & 0xFF;
            if (e >= 100 && e <= 130) ++hits;
        }
        *flag = (hits >= 32) ? 1 : 0;   // 1 = bf16, 0 = fp32
    }
}

// --- 1. per-dst degree; atomic return = rank within dst. 4-way ILP ------------
__global__ void count_kernel(const int* __restrict__ dst, int* __restrict__ deg,
                             unsigned short* __restrict__ rank16) {
    int t = blockIdx.x * blockDim.x + threadIdx.x;
    int e0 = t, e1 = t + CT, e2 = t + 2 * CT, e3 = t + 3 * CT;
    int d0 = dst[e0], d1 = dst[e1], d2 = dst[e2];       // e0..e2 < 1200384 < Ee
    bool g3 = e3 < Ee;
    int d3 = g3 ? dst[e3] : 0;
    int r0 = atomicAdd(&deg[d0], 1);
    int r1 = atomicAdd(&deg[d1], 1);
    int r2 = atomicAdd(&deg[d2], 1);
    int r3 = g3 ? atomicAdd(&deg[d3], 1) : 0;
    rank16[e0] = (unsigned short)r0;
    rank16[e1] = (unsigned short)r1;
    rank16[e2] = (unsigned short)r2;
    if (g3) rank16[e3] = (unsigned short)r3;
}

// --- 2a. per-block exclusive scan + block sums --------------------------------
__global__ __launch_bounds__(256) void scan1_kernel(const int* __restrict__ deg,
                                                    int* __restrict__ offs,
                                                    int* __restrict__ bsum) {
    __shared__ int lsum[4];
    int tid = threadIdx.x, lane = tid & 63, w = tid >> 6;
    int i = blockIdx.x * 256 + tid;
    int v = (i < Nn) ? deg[i] : 0;
    int s = v;
#pragma unroll
    for (int o = 1; o < 64; o <<= 1) { int t = __shfl_up(s, o, 64); if (lane >= o) s += t; }
    if (lane == 63) lsum[w] = s;
    __syncthreads();
    int base = 0;
    for (int j = 0; j < w; ++j) base += lsum[j];
    int excl = base + s - v;
    if (i < Nn) offs[i] = excl;
    if (tid == 255) bsum[blockIdx.x] = excl + v;
}

// --- 2b. scan block sums (NBLK<=256); grand total -> offs[Nn] -----------------
__global__ __launch_bounds__(256) void scan2_kernel(const int* __restrict__ bsum,
                                                    int* __restrict__ carry,
                                                    int* __restrict__ offs) {
    __shared__ int lsum[4];
    int tid = threadIdx.x, lane = tid & 63, w = tid >> 6;
    int v = (tid < NBLK) ? bsum[tid] : 0;
    int s = v;
#pragma unroll
    for (int o = 1; o < 64; o <<= 1) { int t = __shfl_up(s, o, 64); if (lane >= o) s += t; }
    if (lane == 63) lsum[w] = s;
    __syncthreads();
    int base = 0;
    for (int j = 0; j < w; ++j) base += lsum[j];
    int excl = base + s - v;
    if (tid < NBLK) carry[tid] = excl;
    if (tid == 255) offs[Nn] = excl;
}

// --- 2c. add carries ----------------------------------------------------------
__global__ void scan3_kernel(int* __restrict__ offs, const int* __restrict__ carry) {
    int i = blockIdx.x * 256 + threadIdx.x;
    if (i < Nn) offs[i] += carry[blockIdx.x];
}

// --- 3. atomic-free scatter: pos = offs[d] + rank. 4-way ILP ------------------
__global__ void scatter_kernel(const int* __restrict__ src, const int* __restrict__ dst,
                               const int* __restrict__ et, const int* __restrict__ offs,
                               const unsigned short* __restrict__ rank16,
                               unsigned* __restrict__ sorted) {
    int t = blockIdx.x * blockDim.x + threadIdx.x;
#pragma unroll
    for (int k = 0; k < 4; ++k) {
        int e = t + k * CT;
        if (e < Ee) {
            int d = dst[e];
            sorted[offs[d] + (int)rank16[e]] =
                (unsigned)src[e] | ((unsigned)et[e] << 16);
        }
    }
}

// --- 4. layer 1: wave per dst, 16 edges x 4 lanes (full 64B row per group) ----
__global__ __launch_bounds__(256) void l1_kernel(const unsigned* __restrict__ sorted,
                                                 const int* __restrict__ offs,
                                                 const void* __restrict__ w1,
                                                 const void* __restrict__ root1,
                                                 const void* __restrict__ b1,
                                                 const int* __restrict__ flag,
                                                 float* __restrict__ x) {
    __shared__ int   hist[128];
    __shared__ float invh[128];
    int tid = threadIdx.x, w = tid >> 6, lane = tid & 63;
    int ep = lane >> 2, hq = lane & 3;
    int d = blockIdx.x * 4 + w;                  // 12500*4 == Nn
    if (lane < 32) hist[w * 32 + lane] = 0;
    __syncthreads();
    int off = offs[d], deg = offs[d + 1] - off;
    for (int i = lane; i < deg; i += 64)
        atomicAdd(&hist[w * 32 + (sorted[off + i] >> 16)], 1);
    __syncthreads();
    if (lane < 32) {
        int c = hist[w * 32 + lane];
        invh[w * 32 + lane] = c ? 1.0f / (float)c : 0.0f;
    }
    __syncthreads();
    int isbf = *flag;
    float a0 = 0.f, a1 = 0.f, a2 = 0.f, a3 = 0.f;
    if (isbf) {
        for (int i0 = 0; i0 < deg; i0 += 16) {
            int i = i0 + ep;
            if (i < deg) {
                unsigned p = sorted[off + i];
                int rel = p >> 16, s = p & 0xFFFF;
                float inv = invh[w * 32 + rel];
                uint2 v = ((const uint2*)w1)[(size_t)(rel * Nn + s) * 4 + hq];
                a0 += inv * __uint_as_float(v.x << 16);
                a1 += inv * __uint_as_float(v.x & 0xffff0000u);
                a2 += inv * __uint_as_float(v.y << 16);
                a3 += inv * __uint_as_float(v.y & 0xffff0000u);
            }
        }
    } else {
        for (int i0 = 0; i0 < deg; i0 += 16) {
            int i = i0 + ep;
            if (i < deg) {
                unsigned p = sorted[off + i];
                int rel = p >> 16, s = p & 0xFFFF;
                float inv = invh[w * 32 + rel];
                float4 v = ((const float4*)w1)[(size_t)(rel * Nn + s) * 4 + hq];
                a0 += inv * v.x; a1 += inv * v.y; a2 += inv * v.z; a3 += inv * v.w;
            }
        }
    }
#pragma unroll
    for (int o = 4; o < 64; o <<= 1) {
        a0 += __shfl_xor(a0, o, 64); a1 += __shfl_xor(a1, o, 64);
        a2 += __shfl_xor(a2, o, 64); a3 += __shfl_xor(a3, o, 64);
    }
    if (ep == 0) {
        float r0, r1, r2, r3, bb0, bb1, bb2, bb3;
        if (isbf) {
            uint2 rv = ((const uint2*)root1)[(size_t)d * 4 + hq];
            r0 = __uint_as_float(rv.x << 16); r1 = __uint_as_float(rv.x & 0xffff0000u);
            r2 = __uint_as_float(rv.y << 16); r3 = __uint_as_float(rv.y & 0xffff0000u);
            uint2 bv = ((const uint2*)b1)[hq];
            bb0 = __uint_as_float(bv.x << 16); bb1 = __uint_as_float(bv.x & 0xffff0000u);
            bb2 = __uint_as_float(bv.y << 16); bb3 = __uint_as_float(bv.y & 0xffff0000u);
        } else {
            float4 rv = ((const float4*)root1)[(size_t)d * 4 + hq];
            float4 bv = ((const float4*)b1)[hq];
            r0 = rv.x; r1 = rv.y; r2 = rv.z; r3 = rv.w;
            bb0 = bv.x; bb1 = bv.y; bb2 = bv.z; bb3 = bv.w;
        }
        float v0 = a0 + r0 + bb0, v1 = a1 + r1 + bb1;
        float v2 = a2 + r2 + bb2, v3 = a3 + r3 + bb3;
        *(float4*)(x + (size_t)d * Hh + hq * 4) =
            make_float4(fmaxf(v0, 0.f), fmaxf(v1, 0.f), fmaxf(v2, 0.f), fmaxf(v3, 0.f));
    }
}

// --- 5. layer 2 + epilogue: wave per dst, 8 edges x 8 classes, reg dots -------
__global__ __launch_bounds__(256) void l2_kernel(const unsigned* __restrict__ sorted,
                                                 const int* __restrict__ offs,
                                                 const float* __restrict__ x,
                                                 const void* __restrict__ w2,
                                                 const void* __restrict__ root2,
                                                 const void* __restrict__ b2v,
                                                 const int* __restrict__ flag,
                                                 void* __restrict__ out) {
    __shared__ float w2s[32 * 132];   // [rel]*132 + c*16 + h  (pad: ~2-way banks)
    __shared__ float rsh[128];        // root2 [h*8+c]
    __shared__ float b2sh[8];
    __shared__ int   hist[128];
    __shared__ float invh[128];
    int tid = threadIdx.x, w = tid >> 6, lane = tid & 63;
    int isbf = *flag;
    {
        int r = tid >> 3, cc = tid & 7;
        if (isbf) {
            const __hip_bfloat16* W = (const __hip_bfloat16*)w2 + r * 128 + cc;
#pragma unroll
            for (int h = 0; h < 16; ++h) w2s[r * 132 + cc * 16 + h] = b2f(W[h * 8]);
        } else {
            const float* W = (const float*)w2 + r * 128 + cc;
#pragma unroll
            for (int h = 0; h < 16; ++h) w2s[r * 132 + cc * 16 + h] = W[h * 8];
        }
    }
    if (tid < 128) rsh[tid] = isbf ? b2f(((const __hip_bfloat16*)root2)[tid])
                                   : ((const float*)root2)[tid];
    if (tid < 8)   b2sh[tid] = isbf ? b2f(((const __hip_bfloat16*)b2v)[tid])
                                    : ((const float*)b2v)[tid];
    if (lane < 32) hist[w * 32 + lane] = 0;
    __syncthreads();
    int d = blockIdx.x * 4 + w;
    int off = offs[d], deg = offs[d + 1] - off;
    for (int i = lane; i < deg; i += 64)
        atomicAdd(&hist[w * 32 + (sorted[off + i] >> 16)], 1);
    __syncthreads();
    if (lane < 32) {
        int c = hist[w * 32 + lane];
        invh[w * 32 + lane] = c ? 1.0f / (float)c : 0.0f;
    }
    __syncthreads();
    int ep = lane >> 3, c = lane & 7;
    float acc = 0.0f;
    for (int i0 = 0; i0 < deg; i0 += 8) {
        int i = i0 + ep;
        if (i < deg) {
            unsigned p = sorted[off + i];
            int rel = p >> 16, s = p & 0xFFFF;
            float inv = invh[w * 32 + rel];
            const float4* xr = (const float4*)(x + (size_t)s * Hh);
            float4 x0 = xr[0], x1 = xr[1], x2 = xr[2], x3 = xr[3];
            const float4* wv = (const float4*)(w2s + rel * 132 + c * 16);
            float4 w0 = wv[0], w1v = wv[1], w2v = wv[2], w3 = wv[3];
            float dot = x0.x*w0.x + x0.y*w0.y + x0.z*w0.z + x0.w*w0.w
                      + x1.x*w1v.x + x1.y*w1v.y + x1.z*w1v.z + x1.w*w1v.w
                      + x2.x*w2v.x + x2.y*w2v.y + x2.z*w2v.z + x2.w*w2v.w
                      + x3.x*w3.x + x3.y*w3.y + x3.z*w3.z + x3.w*w3.w;
            acc += inv * dot;
        }
    }
    acc += __shfl_xor(acc, 8, 64);
    acc += __shfl_xor(acc, 16, 64);
    acc += __shfl_xor(acc, 32, 64);
    if (ep == 0) {
        const float4* xr = (const float4*)(x + (size_t)d * Hh);
        float4 x0 = xr[0], x1 = xr[1], x2 = xr[2], x3 = xr[3];
        float xv[16] = {x0.x,x0.y,x0.z,x0.w, x1.x,x1.y,x1.z,x1.w,
                        x2.x,x2.y,x2.z,x2.w, x3.x,x3.y,x3.z,x3.w};
        float v = acc + b2sh[c];
#pragma unroll
        for (int h = 0; h < 16; ++h) v += xv[h] * rsh[h * 8 + c];
        float m = v;
#pragma unroll
        for (int o = 1; o < 8; o <<= 1) m = fmaxf(m, __shfl_xor(m, o, 8));
        float ssum = __expf(v - m);
#pragma unroll
        for (int o = 1; o < 8; o <<= 1) ssum += __shfl_xor(ssum, o, 8);
        float res = v - m - __logf(ssum);
        if (isbf) ((__hip_bfloat16*)out)[(size_t)d * Cc + c] = __float2bfloat16(res);
        else      ((float*)out)[(size_t)d * Cc + c] = res;
    }
}

extern "C" void kernel_launch(void* const* d_in, const int* in_sizes, int n_in,
                              void* d_out, int out_size, void* d_ws, size_t ws_size,
                              hipStream_t stream) {
    const int* edge_index = (const int*)d_in[0];     // [2, E]
    const int* src = edge_index;
    const int* dst = edge_index + Ee;
    const int* et  = (const int*)d_in[1];            // [E]
    const void* w1    = d_in[2];  // [R,N,H]
    const void* root1 = d_in[3];  // [N,H]
    const void* b1    = d_in[4];  // [H]
    const void* w2    = d_in[5];  // [R,H,C]
    const void* root2 = d_in[6];  // [H,C]
    const void* b2    = d_in[7];  // [C]

    // ws (~13.2 MB): deg[Nn] | rank16[Ee ushort] | offs[Nn+4] | bsum[256] |
    //                carry[256] | sorted[Ee] | x[Nn*Hh fp32] | flag[1]
    int* deg = (int*)d_ws;
    unsigned short* rank16 = (unsigned short*)(deg + Nn);
    int* offs  = (int*)(rank16 + Ee);
    int* bsum  = offs + Nn + 4;
    int* carry = bsum + 256;
    unsigned* sorted = (unsigned*)(carry + 256);
    float* x   = (float*)(sorted + Ee);
    int* flag  = (int*)(x + (size_t)Nn * Hh);

    hipMemsetAsync(deg, 0, (size_t)Nn * sizeof(int), stream);

    sniff_kernel<<<1, 64, 0, stream>>>((const unsigned short*)w1, flag);
    count_kernel<<<CBLK, 256, 0, stream>>>(dst, deg, rank16);
    scan1_kernel<<<NBLK, 256, 0, stream>>>(deg, offs, bsum);
    scan2_kernel<<<1, 256, 0, stream>>>(bsum, carry, offs);
    scan3_kernel<<<NBLK, 256, 0, stream>>>(offs, carry);
    scatter_kernel<<<CBLK, 256, 0, stream>>>(src, dst, et, offs, rank16, sorted);
    l1_kernel<<<Nn / 4, 256, 0, stream>>>(sorted, offs, w1, root1, b1, flag, x);
    l2_kernel<<<Nn / 4, 256, 0, stream>>>(sorted, offs, x, w2, root2, b2, flag, d_out);
}